// Round 5
// baseline (316057.495 us; speedup 1.0000x reference)
//
#include <hip/hip_runtime.h>
#include <hip/hip_bf16.h>
#include <math.h>

#define BB 256
#define TT 256
#define VV 33
#define HH 512
#define DD 256
#define KKEY 512
#define G4 2048
#define K1 832     // GEMM-K layer1: [a 0:256 | h 256:768 | x 768:801 | pad 801:832]
#define K1A 768    // xcat1 row stride (a+h only)
#define K1X 64     // packed-x row stride (33 data + zero pad)
#define K2 1280    // [hprev 0:512 | a 512:768 | hself 768:1280]
#define CH 32      // attention keys chunk rows
#define KP 260     // klds row stride (fp32), 256 + 4 pad
#define NBLK 512   // persistent grid (2 blocks/CU x 256 CUs, guaranteed by launch_bounds + LDS)

typedef unsigned short u16;
typedef unsigned int u32;
typedef __attribute__((ext_vector_type(8))) short short8;
typedef __attribute__((ext_vector_type(4))) float float4v;

__device__ inline float bf2f(u16 v) {
    union { u32 u; float f; } c; c.u = ((u32)v) << 16; return c.f;
}
__device__ inline u16 f2bf(float f) {
    __hip_bfloat16 h = __float2bfloat16(f);
    union { __hip_bfloat16 h; u16 u; } c; c.h = h; return c.u;
}
__device__ inline void split_bf(float v, u16& hi, u16& lo) {
    hi = f2bf(v);
    lo = f2bf(v - bf2f(hi));
}

// ---------------- weight prep: Wt[col'][k], gate-interleaved columns ----------------
// col' = u*4 + g  <->  original col = g*512 + u
__global__ void prep_v7(const float* __restrict__ W, const float* __restrict__ U,
                        u16* __restrict__ WtH, u16* __restrict__ WtL, int Kd, int mode) {
    long idx = (long)blockIdx.x * blockDim.x + threadIdx.x;
    if (idx >= (long)G4 * Kd) return;
    int colp = (int)(idx / Kd);
    int k = (int)(idx % Kd);
    int col = (colp & 3) * 512 + (colp >> 2);
    float v = 0.f;
    if (mode == 1) {
        if (k < 256)      v = W[(long)(33 + k) * G4 + col];
        else if (k < 768) v = U[(long)(k - 256) * G4 + col];
        else if (k < 801) v = W[(long)(k - 768) * G4 + col];
    } else {
        if (k < 768) v = W[(long)k * G4 + col];
        else         v = U[(long)(k - 768) * G4 + col];
    }
    u16 hi, lo; split_bf(v, hi, lo);
    WtH[idx] = hi; WtL[idx] = lo;
}

// ---------------- Wq^T prep: WqT[d][j] = Wq[j][d], bf16 hi/lo ----------------
__global__ void prep_wq(const float* __restrict__ Wq,
                        u16* __restrict__ WqTH, u16* __restrict__ WqTL) {
    int idx = blockIdx.x * blockDim.x + threadIdx.x;
    if (idx >= DD * HH) return;
    int d = idx / HH, j = idx % HH;
    u16 hi, lo; split_bf(Wq[(long)j * DD + d], hi, lo);
    WqTH[idx] = hi; WqTL[idx] = lo;
}

// ---------------- pre-pack x for ALL t: xP[t][b][64] (33 data, rest zero) ----------------
__global__ void packx_v7(const float* __restrict__ x, u16* __restrict__ xPH, u16* __restrict__ xPL) {
    long idx = (long)blockIdx.x * blockDim.x + threadIdx.x;
    if (idx >= (long)TT * BB * K1X) return;
    int k = (int)(idx % K1X);
    long tb = idx / K1X;
    int b = (int)(tb % BB);
    int t = (int)(tb / BB);
    float v = (k < VV) ? x[((long)b * TT + t) * VV + k] : 0.f;
    u16 hi, lo; split_bf(v, hi, lo);
    xPH[idx] = hi; xPL[idx] = lo;
}

// ---------------- grid barrier (sense-reversing, agent scope) ----------------
__device__ __forceinline__ void gridbar(u32* bar, int tid) {
    __syncthreads();
    if (tid == 0) {
        __threadfence();   // release: block's stores visible device-wide
        u32 gen = __hip_atomic_load(bar + 1, __ATOMIC_RELAXED, __HIP_MEMORY_SCOPE_AGENT);
        u32 old = __hip_atomic_fetch_add(bar, 1u, __ATOMIC_ACQ_REL, __HIP_MEMORY_SCOPE_AGENT);
        if (old == (u32)(NBLK - 1)) {
            __hip_atomic_store(bar, 0u, __ATOMIC_RELAXED, __HIP_MEMORY_SCOPE_AGENT);
            __hip_atomic_store(bar + 1, gen + 1u, __ATOMIC_RELEASE, __HIP_MEMORY_SCOPE_AGENT);
        } else {
            while (__hip_atomic_load(bar + 1, __ATOMIC_ACQUIRE, __HIP_MEMORY_SCOPE_AGENT) == gen)
                __builtin_amdgcn_s_sleep(1);
        }
        __threadfence();   // acquire: invalidate caches so we see other XCDs' stores
    }
    __syncthreads();
}

// ---------------- phase: z-GEMM + LSTM gates (32x32 tile per block) ----------------
__device__ __forceinline__ void zg_phase(
    int bid, int tid,
    u16* AldsH, u16* AldsL, u16* WldsH, u16* WldsL, float* zlds,
    const u16* __restrict__ aH, const u16* __restrict__ aL, int strideA, int Kd,
    const u16* __restrict__ xH, const u16* __restrict__ xL,
    const u16* __restrict__ wH, const u16* __restrict__ wL,
    const float* __restrict__ bias,
    float* __restrict__ c, float* __restrict__ h,
    u16* __restrict__ d0H, u16* __restrict__ d0L, int d0off, int d0stride,
    u16* __restrict__ d1H, u16* __restrict__ d1L, int d1off, int d1stride)
{
    int mt = bid >> 6;    // 0..7
    int nt = bid & 63;    // 0..63
    int M0 = mt * 32, N0 = nt * 32;

    int wave = tid >> 6, lane = tid & 63;
    int lr = lane & 15, lg = lane >> 4;
    int rbase = (wave & 1) * 16, cbase = (wave >> 1) * 16;

    int half = tid >> 7;
    int slot = tid & 127;
    int sr = slot >> 2, sp = slot & 3;

    const u16* aRow = (half ? aL : aH) + (long)(M0 + sr) * strideA;
    const u16* xRow = xH ? ((half ? xL : xH) + (long)(M0 + sr) * K1X) : nullptr;
    const u16* wRow = (half ? wL : wH) + (long)(N0 + sr) * Kd;
    u16* aDst = (half ? AldsL : AldsH) + sr * 40 + sp * 8;
    u16* wDst = (half ? WldsL : WldsH) + sr * 40 + sp * 8;

    auto loadA = [&](int kg) -> uint4 {
        return (xRow && kg >= K1A) ? *(const uint4*)(xRow + (kg - K1A))
                                   : *(const uint4*)(aRow + kg);
    };

    float4v acc = (float4v){0.f, 0.f, 0.f, 0.f};

    uint4 va = loadA(sp * 8);
    uint4 vw = *(const uint4*)(wRow + sp * 8);

    for (int k0 = 0; k0 < Kd; k0 += 32) {
        __syncthreads();
        *(uint4*)aDst = va;
        *(uint4*)wDst = vw;
        if (k0 + 32 < Kd) {
            int kg = k0 + 32 + sp * 8;
            va = loadA(kg);
            vw = *(const uint4*)(wRow + kg);
        }
        __syncthreads();
        // A fragment: m = rbase + (lane&15), k = (lane>>4)*8 + j   [m120-verified]
        short8 ah = *(const short8*)(&AldsH[(rbase + lr) * 40 + lg * 8]);
        short8 al = *(const short8*)(&AldsL[(rbase + lr) * 40 + lg * 8]);
        short8 bh = *(const short8*)(&WldsH[(cbase + lr) * 40 + lg * 8]);
        short8 bl = *(const short8*)(&WldsL[(cbase + lr) * 40 + lg * 8]);
        acc = __builtin_amdgcn_mfma_f32_16x16x32_bf16(ah, bh, acc, 0, 0, 0);
        acc = __builtin_amdgcn_mfma_f32_16x16x32_bf16(ah, bl, acc, 0, 0, 0);
        acc = __builtin_amdgcn_mfma_f32_16x16x32_bf16(al, bh, acc, 0, 0, 0);
    }

    // D: col = lane&15, row = (lane>>4)*4 + r   [m89-verified]
    #pragma unroll
    for (int r = 0; r < 4; r++)
        zlds[(rbase + lg * 4 + r) * 36 + cbase + lr] = acc[r];
    __syncthreads();

    // gates: 1 row x 1 unit per thread
    int um = tid & 7, ml = tid >> 3;       // um 0..7, ml 0..31
    int u = (nt << 3) + um;
    int m = M0 + ml;
    float zi  = zlds[ml * 36 + um * 4 + 0] + bias[u];
    float zf  = zlds[ml * 36 + um * 4 + 1] + bias[512 + u];
    float zg_ = zlds[ml * 36 + um * 4 + 2] + bias[1024 + u];
    float zo  = zlds[ml * 36 + um * 4 + 3] + bias[1536 + u];
    float i_ = 1.f / (1.f + expf(-zi));
    float f_ = 1.f / (1.f + expf(-zf));
    float g_ = tanhf(zg_);
    float o_ = 1.f / (1.f + expf(-zo));
    long idx = (long)m * HH + u;
    float cn = f_ * c[idx] + i_ * g_;
    c[idx] = cn;
    float hn = o_ * tanhf(cn);
    if (h) h[idx] = hn;
    u16 hi_, lo_; split_bf(hn, hi_, lo_);
    if (d0H) {
        d0H[(long)m * d0stride + d0off + u] = hi_;
        d0L[(long)m * d0stride + d0off + u] = lo_;
    }
    d1H[(long)m * d1stride + d1off + u] = hi_;
    d1L[(long)m * d1stride + d1off + u] = lo_;
    __syncthreads();   // LDS reuse safety for next phase in same block
}

// ---------------- phase: q-GEMM q = h_bf16x3 @ WqT + bq (blocks 0..63) ----------------
__device__ __forceinline__ void qg_phase(
    int bid, int tid,
    u16* AldsH, u16* AldsL, u16* WldsH, u16* WldsL,
    const u16* __restrict__ aH, const u16* __restrict__ aL, int strideA,
    const u16* __restrict__ wH, const u16* __restrict__ wL,
    const float* __restrict__ bq, float* __restrict__ qout)
{
    int mt = bid >> 3;    // 0..7
    int nt = bid & 7;     // 0..7
    int M0 = mt * 32, N0 = nt * 32;

    int wave = tid >> 6, lane = tid & 63;
    int lr = lane & 15, lg = lane >> 4;
    int rbase = (wave & 1) * 16, cbase = (wave >> 1) * 16;

    int half = tid >> 7;
    int slot = tid & 127;
    int sr = slot >> 2, sp = slot & 3;

    const u16* aRow = (half ? aL : aH) + (long)(M0 + sr) * strideA;
    const u16* wRow = (half ? wL : wH) + (long)(N0 + sr) * HH;
    u16* aDst = (half ? AldsL : AldsH) + sr * 40 + sp * 8;
    u16* wDst = (half ? WldsL : WldsH) + sr * 40 + sp * 8;

    float4v acc = (float4v){0.f, 0.f, 0.f, 0.f};

    uint4 va = *(const uint4*)(aRow + sp * 8);
    uint4 vw = *(const uint4*)(wRow + sp * 8);

    for (int k0 = 0; k0 < HH; k0 += 32) {
        __syncthreads();
        *(uint4*)aDst = va;
        *(uint4*)wDst = vw;
        if (k0 + 32 < HH) {
            int kg = k0 + 32 + sp * 8;
            va = *(const uint4*)(aRow + kg);
            vw = *(const uint4*)(wRow + kg);
        }
        __syncthreads();
        short8 ah = *(const short8*)(&AldsH[(rbase + lr) * 40 + lg * 8]);
        short8 al = *(const short8*)(&AldsL[(rbase + lr) * 40 + lg * 8]);
        short8 bh = *(const short8*)(&WldsH[(cbase + lr) * 40 + lg * 8]);
        short8 bl = *(const short8*)(&WldsL[(cbase + lr) * 40 + lg * 8]);
        acc = __builtin_amdgcn_mfma_f32_16x16x32_bf16(ah, bh, acc, 0, 0, 0);
        acc = __builtin_amdgcn_mfma_f32_16x16x32_bf16(ah, bl, acc, 0, 0, 0);
        acc = __builtin_amdgcn_mfma_f32_16x16x32_bf16(al, bh, acc, 0, 0, 0);
    }

    #pragma unroll
    for (int r = 0; r < 4; r++) {
        int m = M0 + rbase + lg * 4 + r;
        int col = N0 + cbase + lr;
        qout[(long)m * DD + col] = acc[r] + bq[col];
    }
    __syncthreads();
}

// ---------------- phase: single-pass attention (+ optional out proj), blocks 0..255 ----------------
__device__ __forceinline__ void attn_phase(
    int b, int tid,
    float* klds, float* plds, float* hlds, float* alds,
    const float* __restrict__ qv, const float* __restrict__ keys,
    u16* __restrict__ dH, u16* __restrict__ dL, int doff, int dstride,
    const float* __restrict__ h,
    const float* __restrict__ Wo, const float* __restrict__ bo,
    float* __restrict__ out, int t)
{
    int lane = tid & 63, wave = tid >> 6;

    const float* kb = keys + (long)b * KKEY * DD;
    float4 q4 = *(const float4*)(qv + (long)b * DD + lane * 4);

    float l_run = 0.f, acc = 0.f;

    float4 kv[8];
    #pragma unroll
    for (int i = 0; i < 8; i++)
        kv[i] = *(const float4*)(kb + (long)(wave + 4 * i) * DD + lane * 4);

    for (int k0 = 0; k0 < KKEY; k0 += CH) {
        __syncthreads();   // klds/plds WAR vs previous accumulation
        float pp[8];
        #pragma unroll
        for (int i = 0; i < 8; i++) {
            *(float4*)(&klds[(wave + 4 * i) * KP + lane * 4]) = kv[i];
            pp[i] = kv[i].x * q4.x + kv[i].y * q4.y + kv[i].z * q4.z + kv[i].w * q4.w;
        }
        float4 kn[8];
        if (k0 + CH < KKEY) {
            #pragma unroll
            for (int i = 0; i < 8; i++)
                kn[i] = *(const float4*)(kb + (long)(k0 + CH + wave + 4 * i) * DD + lane * 4);
        }
        #pragma unroll
        for (int i = 0; i < 8; i++) {
            float s = pp[i];
            s += __shfl_xor(s, 32); s += __shfl_xor(s, 16); s += __shfl_xor(s, 8);
            s += __shfl_xor(s, 4);  s += __shfl_xor(s, 2);  s += __shfl_xor(s, 1);
            if (lane == i) plds[wave + 4 * i] = expf(s);
        }
        __syncthreads();
        float a0 = 0.f, a1 = 0.f;
        #pragma unroll
        for (int k = 0; k < CH; k += 4) {
            float4 p4 = *(const float4*)(&plds[k]);
            l_run += (p4.x + p4.y) + (p4.z + p4.w);
            a0 += p4.x * klds[(k + 0) * KP + tid] + p4.z * klds[(k + 2) * KP + tid];
            a1 += p4.y * klds[(k + 1) * KP + tid] + p4.w * klds[(k + 3) * KP + tid];
        }
        acc += a0 + a1;
        #pragma unroll
        for (int i = 0; i < 8; i++) kv[i] = kn[i];
    }

    float av = acc / l_run;
    u16 hi_, lo_; split_bf(av, hi_, lo_);
    dH[(long)b * dstride + doff + tid] = hi_;
    dL[(long)b * dstride + doff + tid] = lo_;

    if (Wo) {
        alds[tid] = av;
        hlds[tid]       = h[(long)b * HH + tid];
        hlds[tid + 256] = h[(long)b * HH + 256 + tid];
        __syncthreads();
        for (int v = wave; v < VV; v += 4) {
            float s = 0.f;
            for (int i = lane; i < HH; i += 64) s += hlds[i] * Wo[(long)i * VV + v];
            for (int i = lane; i < DD; i += 64) s += alds[i] * Wo[(long)(HH + i) * VV + v];
            for (int o = 32; o > 0; o >>= 1) s += __shfl_xor(s, o);
            if (lane == 0) out[((long)b * TT + t) * VV + v] = s + bo[v];
        }
    }
    __syncthreads();
}

// ---------------- persistent fused kernel: all 256 timesteps, 9 phases each ----------------
struct FPms {
    const u16 *xPH, *xPL;
    const u16 *WtH1, *WtL1, *WtH2, *WtL2, *WtH3, *WtL3;
    const u16 *WqTH, *WqTL;
    const float *b1, *b2, *b3, *bq, *bo, *Wo, *keys;
    float *c1, *c2, *c3, *h3, *qv, *out;
    u16 *x1H0, *x1L0, *x1H1, *x1L1;
    u16 *x2H0, *x2L0, *x2H1, *x2L1;
    u16 *x3H0, *x3L0, *x3H1, *x3L1;
    u32 *bar;
};

__global__ __launch_bounds__(256, 2) void fused_v11(FPms P)
{
    __shared__ u16 AldsH[32 * 40];
    __shared__ u16 AldsL[32 * 40];
    __shared__ u16 WldsH[32 * 40];
    __shared__ u16 WldsL[32 * 40];
    __shared__ float zlds[32 * 36];
    __shared__ __align__(16) float klds[CH * KP];
    __shared__ __align__(16) float plds[CH];
    __shared__ __align__(16) float hlds[HH];
    __shared__ __align__(16) float alds[DD];

    int bid = blockIdx.x, tid = threadIdx.x;

    for (int t = 0; t < TT; t++) {
        const int cur = t & 1;
        u16 *x1Hc = cur ? P.x1H1 : P.x1H0, *x1Lc = cur ? P.x1L1 : P.x1L0;
        u16 *x1Hn = cur ? P.x1H0 : P.x1H1, *x1Ln = cur ? P.x1L0 : P.x1L1;
        u16 *x2Hc = cur ? P.x2H1 : P.x2H0, *x2Lc = cur ? P.x2L1 : P.x2L0;
        u16 *x2Hn = cur ? P.x2H0 : P.x2H1, *x2Ln = cur ? P.x2L0 : P.x2L1;
        u16 *x3Hc = cur ? P.x3H1 : P.x3H0, *x3Lc = cur ? P.x3L1 : P.x3L0;
        u16 *x3Hn = cur ? P.x3H0 : P.x3H1, *x3Ln = cur ? P.x3L0 : P.x3L1;

        // P1: zg1  [a3|h1|x_t] -> h1 (bf16 to x2c.hprev, x1n.hself)
        zg_phase(bid, tid, AldsH, AldsL, WldsH, WldsL, zlds,
                 x1Hc, x1Lc, K1A, K1,
                 P.xPH + (long)t * BB * K1X, P.xPL + (long)t * BB * K1X,
                 P.WtH1, P.WtL1, P.b1, P.c1, nullptr,
                 x2Hc, x2Lc, 0, K2,
                 x1Hn, x1Ln, 256, K1A);
        gridbar(P.bar, tid);
        // P2: qg1  (h1 bf16 lives at x2c offset 0)
        if (bid < 64)
            qg_phase(bid, tid, AldsH, AldsL, WldsH, WldsL,
                     x2Hc, x2Lc, K2, P.WqTH, P.WqTL, P.bq, P.qv);
        gridbar(P.bar, tid);
        // P3: attn1 -> x2c.a
        if (bid < BB)
            attn_phase(bid, tid, klds, plds, hlds, alds, P.qv, P.keys,
                       x2Hc, x2Lc, 512, K2,
                       nullptr, nullptr, nullptr, nullptr, 0);
        gridbar(P.bar, tid);
        // P4: zg2
        zg_phase(bid, tid, AldsH, AldsL, WldsH, WldsL, zlds,
                 x2Hc, x2Lc, K2, K2, nullptr, nullptr,
                 P.WtH2, P.WtL2, P.b2, P.c2, nullptr,
                 x3Hc, x3Lc, 0, K2,
                 x2Hn, x2Ln, 768, K2);
        gridbar(P.bar, tid);
        // P5: qg2
        if (bid < 64)
            qg_phase(bid, tid, AldsH, AldsL, WldsH, WldsL,
                     x3Hc, x3Lc, K2, P.WqTH, P.WqTL, P.bq, P.qv);
        gridbar(P.bar, tid);
        // P6: attn2 -> x3c.a
        if (bid < BB)
            attn_phase(bid, tid, klds, plds, hlds, alds, P.qv, P.keys,
                       x3Hc, x3Lc, 512, K2,
                       nullptr, nullptr, nullptr, nullptr, 0);
        gridbar(P.bar, tid);
        // P7: zg3 (h3 fp32 kept for out proj)
        zg_phase(bid, tid, AldsH, AldsL, WldsH, WldsL, zlds,
                 x3Hc, x3Lc, K2, K2, nullptr, nullptr,
                 P.WtH3, P.WtL3, P.b3, P.c3, P.h3,
                 nullptr, nullptr, 0, 0,
                 x3Hn, x3Ln, 768, K2);
        gridbar(P.bar, tid);
        // P8: qg3 (h3 bf16 lives at x3n offset 768)
        if (bid < 64)
            qg_phase(bid, tid, AldsH, AldsL, WldsH, WldsL,
                     x3Hn + 768, x3Ln + 768, K2, P.WqTH, P.WqTL, P.bq, P.qv);
        gridbar(P.bar, tid);
        // P9: attn3 -> x1n.a ; fused out projection
        if (bid < BB)
            attn_phase(bid, tid, klds, plds, hlds, alds, P.qv, P.keys,
                       x1Hn, x1Ln, 0, K1A,
                       P.h3, P.Wo, P.bo, P.out, t);
        gridbar(P.bar, tid);
    }
}

// ---------------- launch ----------------

extern "C" void kernel_launch(void* const* d_in, const int* in_sizes, int n_in,
                              void* d_out, int out_size, void* d_ws, size_t ws_size,
                              hipStream_t stream) {
    const float *x = nullptr, *keys = nullptr, *W1 = nullptr, *U1 = nullptr,
                *b1 = nullptr, *W2 = nullptr, *U2 = nullptr, *b2 = nullptr,
                *W3 = nullptr, *U3 = nullptr, *b3 = nullptr, *Wq = nullptr,
                *bq = nullptr, *Wo = nullptr, *bo = nullptr;
    {
        int cW23 = 0, cU = 0, cb = 0;
        for (int i = 0; i < n_in; i++) {
            const float* q = (const float*)d_in[i];
            switch (in_sizes[i]) {
                case 2162688:  x = q; break;
                case 33554432: keys = q; break;
                case 591872:   W1 = q; break;
                case 1572864:  if (cW23 == 0) W2 = q; else W3 = q; cW23++; break;
                case 1048576:  if (cU == 0) U1 = q; else if (cU == 1) U2 = q; else U3 = q; cU++; break;
                case 2048:     if (cb == 0) b1 = q; else if (cb == 1) b2 = q; else b3 = q; cb++; break;
                case 131072:   Wq = q; break;
                case 256:      bq = q; break;
                case 25344:    Wo = q; break;
                case 33:       bo = q; break;
                default: break;
            }
        }
    }
    float* out = (float*)d_out;

    char* p = (char*)d_ws;
    auto alloc = [&](size_t n) { char* r = p; p += (n + 255) & ~(size_t)255; return r; };
    u16* WtH1 = (u16*)alloc((size_t)G4 * K1 * 2);
    u16* WtL1 = (u16*)alloc((size_t)G4 * K1 * 2);
    u16* WtH2 = (u16*)alloc((size_t)G4 * K2 * 2);
    u16* WtL2 = (u16*)alloc((size_t)G4 * K2 * 2);
    u16* WtH3 = (u16*)alloc((size_t)G4 * K2 * 2);
    u16* WtL3 = (u16*)alloc((size_t)G4 * K2 * 2);
    u16* WqTH = (u16*)alloc((size_t)DD * HH * 2);
    u16* WqTL = (u16*)alloc((size_t)DD * HH * 2);
    u16* xPH = (u16*)alloc((size_t)TT * BB * K1X * 2);
    u16* xPL = (u16*)alloc((size_t)TT * BB * K1X * 2);
    u16* xc1H[2]; u16* xc1L[2]; u16* xc2H[2]; u16* xc2L[2]; u16* xc3H[2]; u16* xc3L[2];
    for (int i = 0; i < 2; i++) {
        xc1H[i] = (u16*)alloc((size_t)BB * K1A * 2);
        xc1L[i] = (u16*)alloc((size_t)BB * K1A * 2);
        xc2H[i] = (u16*)alloc((size_t)BB * K2 * 2);
        xc2L[i] = (u16*)alloc((size_t)BB * K2 * 2);
        xc3H[i] = (u16*)alloc((size_t)BB * K2 * 2);
        xc3L[i] = (u16*)alloc((size_t)BB * K2 * 2);
    }
    float* c1 = (float*)alloc((size_t)BB * HH * 4);
    float* c2 = (float*)alloc((size_t)BB * HH * 4);
    float* c3 = (float*)alloc((size_t)BB * HH * 4);
    float* h3 = (float*)alloc((size_t)BB * HH * 4);
    float* qv = (float*)alloc((size_t)BB * DD * 4);
    u32* bar = (u32*)alloc(256);

    {
        long t1 = (long)G4 * K1;
        prep_v7<<<(int)((t1 + 255) / 256), 256, 0, stream>>>(W1, U1, WtH1, WtL1, K1, 1);
        long t2 = (long)G4 * K2;
        prep_v7<<<(int)((t2 + 255) / 256), 256, 0, stream>>>(W2, U2, WtH2, WtL2, K2, 2);
        prep_v7<<<(int)((t2 + 255) / 256), 256, 0, stream>>>(W3, U3, WtH3, WtL3, K2, 2);
        prep_wq<<<(DD * HH + 255) / 256, 256, 0, stream>>>(Wq, WqTH, WqTL);
        long tx = (long)TT * BB * K1X;
        packx_v7<<<(int)((tx + 255) / 256), 256, 0, stream>>>(x, xPH, xPL);
        hipMemsetAsync(c1, 0, (size_t)BB * HH * 4, stream);
        hipMemsetAsync(c2, 0, (size_t)BB * HH * 4, stream);
        hipMemsetAsync(c3, 0, (size_t)BB * HH * 4, stream);
        hipMemsetAsync(xc1H[0], 0, (size_t)BB * K1A * 2, stream);
        hipMemsetAsync(xc1L[0], 0, (size_t)BB * K1A * 2, stream);
        hipMemsetAsync(xc2H[0], 0, (size_t)BB * K2 * 2, stream);
        hipMemsetAsync(xc2L[0], 0, (size_t)BB * K2 * 2, stream);
        hipMemsetAsync(xc3H[0], 0, (size_t)BB * K2 * 2, stream);
        hipMemsetAsync(xc3L[0], 0, (size_t)BB * K2 * 2, stream);
        hipMemsetAsync(bar, 0, 256, stream);
    }

    FPms fp;
    fp.xPH = xPH; fp.xPL = xPL;
    fp.WtH1 = WtH1; fp.WtL1 = WtL1;
    fp.WtH2 = WtH2; fp.WtL2 = WtL2;
    fp.WtH3 = WtH3; fp.WtL3 = WtL3;
    fp.WqTH = WqTH; fp.WqTL = WqTL;
    fp.b1 = b1; fp.b2 = b2; fp.b3 = b3; fp.bq = bq; fp.bo = bo;
    fp.Wo = Wo; fp.keys = keys;
    fp.c1 = c1; fp.c2 = c2; fp.c3 = c3; fp.h3 = h3; fp.qv = qv; fp.out = out;
    fp.x1H0 = xc1H[0]; fp.x1L0 = xc1L[0]; fp.x1H1 = xc1H[1]; fp.x1L1 = xc1L[1];
    fp.x2H0 = xc2H[0]; fp.x2L0 = xc2L[0]; fp.x2H1 = xc2H[1]; fp.x2L1 = xc2L[1];
    fp.x3H0 = xc3H[0]; fp.x3L0 = xc3L[0]; fp.x3H1 = xc3H[1]; fp.x3L1 = xc3L[1];
    fp.bar = bar;

    fused_v11<<<dim3(NBLK), dim3(256), 0, stream>>>(fp);
}

// Round 6
// 93765.167 us; speedup vs baseline: 3.3707x; 3.3707x over previous
//
#include <hip/hip_runtime.h>
#include <hip/hip_bf16.h>
#include <math.h>

#define BB 256
#define TT 256
#define VV 33
#define HH 512
#define DD 256
#define KKEY 512
#define G4 2048
#define K1 832     // GEMM-K layer1: [a 0:256 | h 256:768 | x 768:801 | pad 801:832]
#define K1A 768    // xcat1 row stride (a+h only)
#define K1X 64     // packed-x row stride (33 data + zero pad)
#define K2 1280    // [hprev 0:512 | a 512:768 | hself 768:1280]
#define CH 32      // attention keys chunk rows
#define KP 260     // klds row stride (fp32), 256 + 4 pad
#define NBLK 512   // persistent grid (2 blocks/CU x 256 CUs)

typedef unsigned short u16;
typedef unsigned int u32;
typedef unsigned long long u64;
typedef __attribute__((ext_vector_type(8))) short short8;
typedef __attribute__((ext_vector_type(4))) float float4v;

__device__ inline float bf2f(u16 v) {
    union { u32 u; float f; } c; c.u = ((u32)v) << 16; return c.f;
}
__device__ inline u16 f2bf(float f) {
    __hip_bfloat16 h = __float2bfloat16(f);
    union { __hip_bfloat16 h; u16 u; } c; c.h = h; return c.u;
}
__device__ inline void split_bf(float v, u16& hi, u16& lo) {
    hi = f2bf(v);
    lo = f2bf(v - bf2f(hi));
}

// ---- device-coherent (sc0 sc1) access helpers: bypass L1/L2, hit LLC coherence point ----
__device__ __forceinline__ uint4 ld16sc(const void* p) {
    const u64* q = (const u64*)p;
    u64 a = __hip_atomic_load(q,     __ATOMIC_RELAXED, __HIP_MEMORY_SCOPE_AGENT);
    u64 b = __hip_atomic_load(q + 1, __ATOMIC_RELAXED, __HIP_MEMORY_SCOPE_AGENT);
    uint4 r;
    r.x = (u32)a; r.y = (u32)(a >> 32);
    r.z = (u32)b; r.w = (u32)(b >> 32);
    return r;
}
__device__ __forceinline__ float4 ld16fsc(const float* p) {
    uint4 r = ld16sc(p);
    union { uint4 u; float4 f; } c; c.u = r; return c.f;
}
__device__ __forceinline__ float ld4fsc(const float* p) {
    u32 v = __hip_atomic_load((const u32*)p, __ATOMIC_RELAXED, __HIP_MEMORY_SCOPE_AGENT);
    union { u32 u; float f; } c; c.u = v; return c.f;
}
__device__ __forceinline__ void st16sc(u16* p, u16 v) {
    asm volatile("global_store_short %0, %1, off sc0 sc1" :: "v"(p), "v"(v) : "memory");
}
__device__ __forceinline__ void st32sc(float* p, float v) {
    asm volatile("global_store_dword %0, %1, off sc0 sc1" :: "v"(p), "v"(v) : "memory");
}

// ---------------- weight prep: Wt[col'][k], gate-interleaved columns ----------------
// col' = u*4 + g  <->  original col = g*512 + u
__global__ void prep_v7(const float* __restrict__ W, const float* __restrict__ U,
                        u16* __restrict__ WtH, u16* __restrict__ WtL, int Kd, int mode) {
    long idx = (long)blockIdx.x * blockDim.x + threadIdx.x;
    if (idx >= (long)G4 * Kd) return;
    int colp = (int)(idx / Kd);
    int k = (int)(idx % Kd);
    int col = (colp & 3) * 512 + (colp >> 2);
    float v = 0.f;
    if (mode == 1) {
        if (k < 256)      v = W[(long)(33 + k) * G4 + col];
        else if (k < 768) v = U[(long)(k - 256) * G4 + col];
        else if (k < 801) v = W[(long)(k - 768) * G4 + col];
    } else {
        if (k < 768) v = W[(long)k * G4 + col];
        else         v = U[(long)(k - 768) * G4 + col];
    }
    u16 hi, lo; split_bf(v, hi, lo);
    WtH[idx] = hi; WtL[idx] = lo;
}

// ---------------- Wq^T prep: WqT[d][j] = Wq[j][d], bf16 hi/lo ----------------
__global__ void prep_wq(const float* __restrict__ Wq,
                        u16* __restrict__ WqTH, u16* __restrict__ WqTL) {
    int idx = blockIdx.x * blockDim.x + threadIdx.x;
    if (idx >= DD * HH) return;
    int d = idx / HH, j = idx % HH;
    u16 hi, lo; split_bf(Wq[(long)j * DD + d], hi, lo);
    WqTH[idx] = hi; WqTL[idx] = lo;
}

// ---------------- pre-pack x for ALL t: xP[t][b][64] (33 data, rest zero) ----------------
__global__ void packx_v7(const float* __restrict__ x, u16* __restrict__ xPH, u16* __restrict__ xPL) {
    long idx = (long)blockIdx.x * blockDim.x + threadIdx.x;
    if (idx >= (long)TT * BB * K1X) return;
    int k = (int)(idx % K1X);
    long tb = idx / K1X;
    int b = (int)(tb % BB);
    int t = (int)(tb / BB);
    float v = (k < VV) ? x[((long)b * TT + t) * VV + k] : 0.f;
    u16 hi, lo; split_bf(v, hi, lo);
    xPH[idx] = hi; xPL[idx] = lo;
}

// ---------------- grid barrier: monotonic counter, RELAXED atomics only ----------------
// No fences: cross-phase data goes through sc0sc1 ops (LLC-coherent); L2 stays hot.
__device__ __forceinline__ void gridbar(u32* bar, int tid, u32 target) {
    asm volatile("s_waitcnt vmcnt(0)" ::: "memory");   // drain this wave's sc1 stores
    __syncthreads();                                    // all waves drained (compiler adds waits)
    if (tid == 0) {
        __hip_atomic_fetch_add(bar, 1u, __ATOMIC_RELAXED, __HIP_MEMORY_SCOPE_AGENT);
        while (__hip_atomic_load(bar, __ATOMIC_RELAXED, __HIP_MEMORY_SCOPE_AGENT) < target)
            __builtin_amdgcn_s_sleep(2);
    }
    __syncthreads();
}

// ---------------- phase: z-GEMM + LSTM gates (32x32 tile per block) ----------------
__device__ __forceinline__ void zg_phase(
    int bid, int tid,
    u16* AldsH, u16* AldsL, u16* WldsH, u16* WldsL, float* zlds,
    const u16* __restrict__ aH, const u16* __restrict__ aL, int strideA, int Kd,
    const u16* __restrict__ xH, const u16* __restrict__ xL,
    const u16* __restrict__ wH, const u16* __restrict__ wL,
    const float* __restrict__ bias,
    float* __restrict__ c, float* __restrict__ h,
    u16* __restrict__ d0H, u16* __restrict__ d0L, int d0off, int d0stride,
    u16* __restrict__ d1H, u16* __restrict__ d1L, int d1off, int d1stride)
{
    int mt = bid >> 6;    // 0..7
    int nt = bid & 63;    // 0..63
    int M0 = mt * 32, N0 = nt * 32;

    int wave = tid >> 6, lane = tid & 63;
    int lr = lane & 15, lg = lane >> 4;
    int rbase = (wave & 1) * 16, cbase = (wave >> 1) * 16;

    int half = tid >> 7;
    int slot = tid & 127;
    int sr = slot >> 2, sp = slot & 3;

    const u16* aRow = (half ? aL : aH) + (long)(M0 + sr) * strideA;
    const u16* xRow = xH ? ((half ? xL : xH) + (long)(M0 + sr) * K1X) : nullptr;
    const u16* wRow = (half ? wL : wH) + (long)(N0 + sr) * Kd;
    u16* aDst = (half ? AldsL : AldsH) + sr * 40 + sp * 8;
    u16* wDst = (half ? WldsL : WldsH) + sr * 40 + sp * 8;

    // xcat rows: device-coherent loads (cross-XCD producers); xP rows: plain (read-only)
    auto loadA = [&](int kg) -> uint4 {
        if (xRow && kg >= K1A) return *(const uint4*)(xRow + (kg - K1A));
        return ld16sc(aRow + kg);
    };

    float4v acc = (float4v){0.f, 0.f, 0.f, 0.f};

    uint4 va = loadA(sp * 8);
    uint4 vw = *(const uint4*)(wRow + sp * 8);

    for (int k0 = 0; k0 < Kd; k0 += 32) {
        __syncthreads();
        *(uint4*)aDst = va;
        *(uint4*)wDst = vw;
        if (k0 + 32 < Kd) {
            int kg = k0 + 32 + sp * 8;
            va = loadA(kg);
            vw = *(const uint4*)(wRow + kg);
        }
        __syncthreads();
        // A fragment: m = rbase + (lane&15), k = (lane>>4)*8 + j   [m120-verified]
        short8 ah = *(const short8*)(&AldsH[(rbase + lr) * 40 + lg * 8]);
        short8 al = *(const short8*)(&AldsL[(rbase + lr) * 40 + lg * 8]);
        short8 bh = *(const short8*)(&WldsH[(cbase + lr) * 40 + lg * 8]);
        short8 bl = *(const short8*)(&WldsL[(cbase + lr) * 40 + lg * 8]);
        acc = __builtin_amdgcn_mfma_f32_16x16x32_bf16(ah, bh, acc, 0, 0, 0);
        acc = __builtin_amdgcn_mfma_f32_16x16x32_bf16(ah, bl, acc, 0, 0, 0);
        acc = __builtin_amdgcn_mfma_f32_16x16x32_bf16(al, bh, acc, 0, 0, 0);
    }

    // D: col = lane&15, row = (lane>>4)*4 + r   [m89-verified]
    #pragma unroll
    for (int r = 0; r < 4; r++)
        zlds[(rbase + lg * 4 + r) * 36 + cbase + lr] = acc[r];
    __syncthreads();

    // gates: 1 row x 1 unit per thread
    int um = tid & 7, ml = tid >> 3;       // um 0..7, ml 0..31
    int u = (nt << 3) + um;
    int m = M0 + ml;
    float zi  = zlds[ml * 36 + um * 4 + 0] + bias[u];
    float zf  = zlds[ml * 36 + um * 4 + 1] + bias[512 + u];
    float zg_ = zlds[ml * 36 + um * 4 + 2] + bias[1024 + u];
    float zo  = zlds[ml * 36 + um * 4 + 3] + bias[1536 + u];
    float i_ = 1.f / (1.f + expf(-zi));
    float f_ = 1.f / (1.f + expf(-zf));
    float g_ = tanhf(zg_);
    float o_ = 1.f / (1.f + expf(-zo));
    long idx = (long)m * HH + u;
    float cn = f_ * c[idx] + i_ * g_;      // c is block-private across steps: plain
    c[idx] = cn;
    float hn = o_ * tanhf(cn);
    if (h) st32sc(h + idx, hn);            // h3 crosses blocks
    u16 hi_, lo_; split_bf(hn, hi_, lo_);
    if (d0H) {
        st16sc(d0H + (long)m * d0stride + d0off + u, hi_);
        st16sc(d0L + (long)m * d0stride + d0off + u, lo_);
    }
    st16sc(d1H + (long)m * d1stride + d1off + u, hi_);
    st16sc(d1L + (long)m * d1stride + d1off + u, lo_);
    __syncthreads();   // LDS reuse safety for next phase in same block
}

// ---------------- phase: q-GEMM q = h_bf16x3 @ WqT + bq (blocks 0..63) ----------------
__device__ __forceinline__ void qg_phase(
    int bid, int tid,
    u16* AldsH, u16* AldsL, u16* WldsH, u16* WldsL,
    const u16* __restrict__ aH, const u16* __restrict__ aL, int strideA,
    const u16* __restrict__ wH, const u16* __restrict__ wL,
    const float* __restrict__ bq, float* __restrict__ qout)
{
    int mt = bid >> 3;    // 0..7
    int nt = bid & 7;     // 0..7
    int M0 = mt * 32, N0 = nt * 32;

    int wave = tid >> 6, lane = tid & 63;
    int lr = lane & 15, lg = lane >> 4;
    int rbase = (wave & 1) * 16, cbase = (wave >> 1) * 16;

    int half = tid >> 7;
    int slot = tid & 127;
    int sr = slot >> 2, sp = slot & 3;

    const u16* aRow = (half ? aL : aH) + (long)(M0 + sr) * strideA;
    const u16* wRow = (half ? wL : wH) + (long)(N0 + sr) * HH;
    u16* aDst = (half ? AldsL : AldsH) + sr * 40 + sp * 8;
    u16* wDst = (half ? WldsL : WldsH) + sr * 40 + sp * 8;

    float4v acc = (float4v){0.f, 0.f, 0.f, 0.f};

    uint4 va = ld16sc(aRow + sp * 8);
    uint4 vw = *(const uint4*)(wRow + sp * 8);

    for (int k0 = 0; k0 < HH; k0 += 32) {
        __syncthreads();
        *(uint4*)aDst = va;
        *(uint4*)wDst = vw;
        if (k0 + 32 < HH) {
            int kg = k0 + 32 + sp * 8;
            va = ld16sc(aRow + kg);
            vw = *(const uint4*)(wRow + kg);
        }
        __syncthreads();
        short8 ah = *(const short8*)(&AldsH[(rbase + lr) * 40 + lg * 8]);
        short8 al = *(const short8*)(&AldsL[(rbase + lr) * 40 + lg * 8]);
        short8 bh = *(const short8*)(&WldsH[(cbase + lr) * 40 + lg * 8]);
        short8 bl = *(const short8*)(&WldsL[(cbase + lr) * 40 + lg * 8]);
        acc = __builtin_amdgcn_mfma_f32_16x16x32_bf16(ah, bh, acc, 0, 0, 0);
        acc = __builtin_amdgcn_mfma_f32_16x16x32_bf16(ah, bl, acc, 0, 0, 0);
        acc = __builtin_amdgcn_mfma_f32_16x16x32_bf16(al, bh, acc, 0, 0, 0);
    }

    #pragma unroll
    for (int r = 0; r < 4; r++) {
        int m = M0 + rbase + lg * 4 + r;
        int col = N0 + cbase + lr;
        st32sc(qout + (long)m * DD + col, acc[r] + bq[col]);
    }
    __syncthreads();
}

// ---------------- phase: single-pass attention (+ optional out proj), blocks 0..255 ----------------
__device__ __forceinline__ void attn_phase(
    int b, int tid,
    float* klds, float* plds, float* hlds, float* alds,
    const float* __restrict__ qv, const float* __restrict__ keys,
    u16* __restrict__ dH, u16* __restrict__ dL, int doff, int dstride,
    const float* __restrict__ h,
    const float* __restrict__ Wo, const float* __restrict__ bo,
    float* __restrict__ out, int t)
{
    int lane = tid & 63, wave = tid >> 6;

    const float* kb = keys + (long)b * KKEY * DD;
    float4 q4 = ld16fsc(qv + (long)b * DD + lane * 4);

    float l_run = 0.f, acc = 0.f;

    float4 kv[8];
    #pragma unroll
    for (int i = 0; i < 8; i++)
        kv[i] = *(const float4*)(kb + (long)(wave + 4 * i) * DD + lane * 4);

    for (int k0 = 0; k0 < KKEY; k0 += CH) {
        __syncthreads();   // klds/plds WAR vs previous accumulation
        float pp[8];
        #pragma unroll
        for (int i = 0; i < 8; i++) {
            *(float4*)(&klds[(wave + 4 * i) * KP + lane * 4]) = kv[i];
            pp[i] = kv[i].x * q4.x + kv[i].y * q4.y + kv[i].z * q4.z + kv[i].w * q4.w;
        }
        float4 kn[8];
        if (k0 + CH < KKEY) {
            #pragma unroll
            for (int i = 0; i < 8; i++)
                kn[i] = *(const float4*)(kb + (long)(k0 + CH + wave + 4 * i) * DD + lane * 4);
        }
        #pragma unroll
        for (int i = 0; i < 8; i++) {
            float s = pp[i];
            s += __shfl_xor(s, 32); s += __shfl_xor(s, 16); s += __shfl_xor(s, 8);
            s += __shfl_xor(s, 4);  s += __shfl_xor(s, 2);  s += __shfl_xor(s, 1);
            if (lane == i) plds[wave + 4 * i] = expf(s);
        }
        __syncthreads();
        float a0 = 0.f, a1 = 0.f;
        #pragma unroll
        for (int k = 0; k < CH; k += 4) {
            float4 p4 = *(const float4*)(&plds[k]);
            l_run += (p4.x + p4.y) + (p4.z + p4.w);
            a0 += p4.x * klds[(k + 0) * KP + tid] + p4.z * klds[(k + 2) * KP + tid];
            a1 += p4.y * klds[(k + 1) * KP + tid] + p4.w * klds[(k + 3) * KP + tid];
        }
        acc += a0 + a1;
        #pragma unroll
        for (int i = 0; i < 8; i++) kv[i] = kn[i];
    }

    float av = acc / l_run;
    u16 hi_, lo_; split_bf(av, hi_, lo_);
    st16sc(dH + (long)b * dstride + doff + tid, hi_);
    st16sc(dL + (long)b * dstride + doff + tid, lo_);

    if (Wo) {
        alds[tid] = av;
        hlds[tid]       = ld4fsc(h + (long)b * HH + tid);
        hlds[tid + 256] = ld4fsc(h + (long)b * HH + 256 + tid);
        __syncthreads();
        for (int v = wave; v < VV; v += 4) {
            float s = 0.f;
            for (int i = lane; i < HH; i += 64) s += hlds[i] * Wo[(long)i * VV + v];
            for (int i = lane; i < DD; i += 64) s += alds[i] * Wo[(long)(HH + i) * VV + v];
            for (int o = 32; o > 0; o >>= 1) s += __shfl_xor(s, o);
            if (lane == 0) out[((long)b * TT + t) * VV + v] = s + bo[v];
        }
    }
    __syncthreads();
}

// ---------------- persistent fused kernel: all 256 timesteps, 9 phases each ----------------
struct FPms {
    const u16 *xPH, *xPL;
    const u16 *WtH1, *WtL1, *WtH2, *WtL2, *WtH3, *WtL3;
    const u16 *WqTH, *WqTL;
    const float *b1, *b2, *b3, *bq, *bo, *Wo, *keys;
    float *c1, *c2, *c3, *h3, *qv, *out;
    u16 *x1H0, *x1L0, *x1H1, *x1L1;
    u16 *x2H0, *x2L0, *x2H1, *x2L1;
    u16 *x3H0, *x3L0, *x3H1, *x3L1;
    u32 *bar;
};

__global__ __launch_bounds__(256, 2) void fused_v12(FPms P)
{
    __shared__ u16 AldsH[32 * 40];
    __shared__ u16 AldsL[32 * 40];
    __shared__ u16 WldsH[32 * 40];
    __shared__ u16 WldsL[32 * 40];
    __shared__ float zlds[32 * 36];
    __shared__ __align__(16) float klds[CH * KP];
    __shared__ __align__(16) float plds[CH];
    __shared__ __align__(16) float hlds[HH];
    __shared__ __align__(16) float alds[DD];

    int bid = blockIdx.x, tid = threadIdx.x;
    u32 tgt = 0;

    for (int t = 0; t < TT; t++) {
        const int cur = t & 1;
        u16 *x1Hc = cur ? P.x1H1 : P.x1H0, *x1Lc = cur ? P.x1L1 : P.x1L0;
        u16 *x1Hn = cur ? P.x1H0 : P.x1H1, *x1Ln = cur ? P.x1L0 : P.x1L1;
        u16 *x2Hc = cur ? P.x2H1 : P.x2H0, *x2Lc = cur ? P.x2L1 : P.x2L0;
        u16 *x2Hn = cur ? P.x2H0 : P.x2H1, *x2Ln = cur ? P.x2L0 : P.x2L1;
        u16 *x3Hc = cur ? P.x3H1 : P.x3H0, *x3Lc = cur ? P.x3L1 : P.x3L0;
        u16 *x3Hn = cur ? P.x3H0 : P.x3H1, *x3Ln = cur ? P.x3L0 : P.x3L1;

        // P1: zg1  [a3|h1|x_t] -> h1 (bf16 to x2c.hprev, x1n.hself)
        zg_phase(bid, tid, AldsH, AldsL, WldsH, WldsL, zlds,
                 x1Hc, x1Lc, K1A, K1,
                 P.xPH + (long)t * BB * K1X, P.xPL + (long)t * BB * K1X,
                 P.WtH1, P.WtL1, P.b1, P.c1, nullptr,
                 x2Hc, x2Lc, 0, K2,
                 x1Hn, x1Ln, 256, K1A);
        tgt += NBLK; gridbar(P.bar, tid, tgt);
        // P2: qg1  (h1 bf16 lives at x2c offset 0)
        if (bid < 64)
            qg_phase(bid, tid, AldsH, AldsL, WldsH, WldsL,
                     x2Hc, x2Lc, K2, P.WqTH, P.WqTL, P.bq, P.qv);
        tgt += NBLK; gridbar(P.bar, tid, tgt);
        // P3: attn1 -> x2c.a
        if (bid < BB)
            attn_phase(bid, tid, klds, plds, hlds, alds, P.qv, P.keys,
                       x2Hc, x2Lc, 512, K2,
                       nullptr, nullptr, nullptr, nullptr, 0);
        tgt += NBLK; gridbar(P.bar, tid, tgt);
        // P4: zg2
        zg_phase(bid, tid, AldsH, AldsL, WldsH, WldsL, zlds,
                 x2Hc, x2Lc, K2, K2, nullptr, nullptr,
                 P.WtH2, P.WtL2, P.b2, P.c2, nullptr,
                 x3Hc, x3Lc, 0, K2,
                 x2Hn, x2Ln, 768, K2);
        tgt += NBLK; gridbar(P.bar, tid, tgt);
        // P5: qg2
        if (bid < 64)
            qg_phase(bid, tid, AldsH, AldsL, WldsH, WldsL,
                     x3Hc, x3Lc, K2, P.WqTH, P.WqTL, P.bq, P.qv);
        tgt += NBLK; gridbar(P.bar, tid, tgt);
        // P6: attn2 -> x3c.a
        if (bid < BB)
            attn_phase(bid, tid, klds, plds, hlds, alds, P.qv, P.keys,
                       x3Hc, x3Lc, 512, K2,
                       nullptr, nullptr, nullptr, nullptr, 0);
        tgt += NBLK; gridbar(P.bar, tid, tgt);
        // P7: zg3 (h3 fp32 kept for out proj)
        zg_phase(bid, tid, AldsH, AldsL, WldsH, WldsL, zlds,
                 x3Hc, x3Lc, K2, K2, nullptr, nullptr,
                 P.WtH3, P.WtL3, P.b3, P.c3, P.h3,
                 nullptr, nullptr, 0, 0,
                 x3Hn, x3Ln, 768, K2);
        tgt += NBLK; gridbar(P.bar, tid, tgt);
        // P8: qg3 (h3 bf16 lives at x3n offset 768)
        if (bid < 64)
            qg_phase(bid, tid, AldsH, AldsL, WldsH, WldsL,
                     x3Hn + 768, x3Ln + 768, K2, P.WqTH, P.WqTL, P.bq, P.qv);
        tgt += NBLK; gridbar(P.bar, tid, tgt);
        // P9: attn3 -> x1n.a ; fused out projection
        if (bid < BB)
            attn_phase(bid, tid, klds, plds, hlds, alds, P.qv, P.keys,
                       x1Hn, x1Ln, 0, K1A,
                       P.h3, P.Wo, P.bo, P.out, t);
        tgt += NBLK; gridbar(P.bar, tid, tgt);
    }
}

// ---------------- launch ----------------

extern "C" void kernel_launch(void* const* d_in, const int* in_sizes, int n_in,
                              void* d_out, int out_size, void* d_ws, size_t ws_size,
                              hipStream_t stream) {
    const float *x = nullptr, *keys = nullptr, *W1 = nullptr, *U1 = nullptr,
                *b1 = nullptr, *W2 = nullptr, *U2 = nullptr, *b2 = nullptr,
                *W3 = nullptr, *U3 = nullptr, *b3 = nullptr, *Wq = nullptr,
                *bq = nullptr, *Wo = nullptr, *bo = nullptr;
    {
        int cW23 = 0, cU = 0, cb = 0;
        for (int i = 0; i < n_in; i++) {
            const float* q = (const float*)d_in[i];
            switch (in_sizes[i]) {
                case 2162688:  x = q; break;
                case 33554432: keys = q; break;
                case 591872:   W1 = q; break;
                case 1572864:  if (cW23 == 0) W2 = q; else W3 = q; cW23++; break;
                case 1048576:  if (cU == 0) U1 = q; else if (cU == 1) U2 = q; else U3 = q; cU++; break;
                case 2048:     if (cb == 0) b1 = q; else if (cb == 1) b2 = q; else b3 = q; cb++; break;
                case 131072:   Wq = q; break;
                case 256:      bq = q; break;
                case 25344:    Wo = q; break;
                case 33:       bo = q; break;
                default: break;
            }
        }
    }
    float* out = (float*)d_out;

    char* p = (char*)d_ws;
    auto alloc = [&](size_t n) { char* r = p; p += (n + 255) & ~(size_t)255; return r; };
    u16* WtH1 = (u16*)alloc((size_t)G4 * K1 * 2);
    u16* WtL1 = (u16*)alloc((size_t)G4 * K1 * 2);
    u16* WtH2 = (u16*)alloc((size_t)G4 * K2 * 2);
    u16* WtL2 = (u16*)alloc((size_t)G4 * K2 * 2);
    u16* WtH3 = (u16*)alloc((size_t)G4 * K2 * 2);
    u16* WtL3 = (u16*)alloc((size_t)G4 * K2 * 2);
    u16* WqTH = (u16*)alloc((size_t)DD * HH * 2);
    u16* WqTL = (u16*)alloc((size_t)DD * HH * 2);
    u16* xPH = (u16*)alloc((size_t)TT * BB * K1X * 2);
    u16* xPL = (u16*)alloc((size_t)TT * BB * K1X * 2);
    u16* xc1H[2]; u16* xc1L[2]; u16* xc2H[2]; u16* xc2L[2]; u16* xc3H[2]; u16* xc3L[2];
    for (int i = 0; i < 2; i++) {
        xc1H[i] = (u16*)alloc((size_t)BB * K1A * 2);
        xc1L[i] = (u16*)alloc((size_t)BB * K1A * 2);
        xc2H[i] = (u16*)alloc((size_t)BB * K2 * 2);
        xc2L[i] = (u16*)alloc((size_t)BB * K2 * 2);
        xc3H[i] = (u16*)alloc((size_t)BB * K2 * 2);
        xc3L[i] = (u16*)alloc((size_t)BB * K2 * 2);
    }
    float* c1 = (float*)alloc((size_t)BB * HH * 4);
    float* c2 = (float*)alloc((size_t)BB * HH * 4);
    float* c3 = (float*)alloc((size_t)BB * HH * 4);
    float* h3 = (float*)alloc((size_t)BB * HH * 4);
    float* qv = (float*)alloc((size_t)BB * DD * 4);
    u32* bar = (u32*)alloc(256);

    {
        long t1 = (long)G4 * K1;
        prep_v7<<<(int)((t1 + 255) / 256), 256, 0, stream>>>(W1, U1, WtH1, WtL1, K1, 1);
        long t2 = (long)G4 * K2;
        prep_v7<<<(int)((t2 + 255) / 256), 256, 0, stream>>>(W2, U2, WtH2, WtL2, K2, 2);
        prep_v7<<<(int)((t2 + 255) / 256), 256, 0, stream>>>(W3, U3, WtH3, WtL3, K2, 2);
        prep_wq<<<(DD * HH + 255) / 256, 256, 0, stream>>>(Wq, WqTH, WqTL);
        long tx = (long)TT * BB * K1X;
        packx_v7<<<(int)((tx + 255) / 256), 256, 0, stream>>>(x, xPH, xPL);
        hipMemsetAsync(c1, 0, (size_t)BB * HH * 4, stream);
        hipMemsetAsync(c2, 0, (size_t)BB * HH * 4, stream);
        hipMemsetAsync(c3, 0, (size_t)BB * HH * 4, stream);
        hipMemsetAsync(xc1H[0], 0, (size_t)BB * K1A * 2, stream);
        hipMemsetAsync(xc1L[0], 0, (size_t)BB * K1A * 2, stream);
        hipMemsetAsync(xc2H[0], 0, (size_t)BB * K2 * 2, stream);
        hipMemsetAsync(xc2L[0], 0, (size_t)BB * K2 * 2, stream);
        hipMemsetAsync(xc3H[0], 0, (size_t)BB * K2 * 2, stream);
        hipMemsetAsync(xc3L[0], 0, (size_t)BB * K2 * 2, stream);
        hipMemsetAsync(bar, 0, 256, stream);
    }

    FPms fp;
    fp.xPH = xPH; fp.xPL = xPL;
    fp.WtH1 = WtH1; fp.WtL1 = WtL1;
    fp.WtH2 = WtH2; fp.WtL2 = WtL2;
    fp.WtH3 = WtH3; fp.WtL3 = WtL3;
    fp.WqTH = WqTH; fp.WqTL = WqTL;
    fp.b1 = b1; fp.b2 = b2; fp.b3 = b3; fp.bq = bq; fp.bo = bo;
    fp.Wo = Wo; fp.keys = keys;
    fp.c1 = c1; fp.c2 = c2; fp.c3 = c3; fp.h3 = h3; fp.qv = qv; fp.out = out;
    fp.x1H0 = xc1H[0]; fp.x1L0 = xc1L[0]; fp.x1H1 = xc1H[1]; fp.x1L1 = xc1L[1];
    fp.x2H0 = xc2H[0]; fp.x2L0 = xc2L[0]; fp.x2H1 = xc2H[1]; fp.x2L1 = xc2L[1];
    fp.x3H0 = xc3H[0]; fp.x3L0 = xc3L[0]; fp.x3H1 = xc3H[1]; fp.x3L1 = xc3L[1];
    fp.bar = bar;

    fused_v12<<<dim3(NBLK), dim3(256), 0, stream>>>(fp);
}